// Round 2
// baseline (244.086 us; speedup 1.0000x reference)
//
#include <hip/hip_runtime.h>

// Causal FIR conv via FFT (n_fft = 131072), four-step N = 512 x 256,
// transpose-free, batch-packed (2 real rows -> 1 complex row).
// v7: fwd_cols rewritten as 16(reg) x 32(thread) four-step:
//   X[c+16d] = FFT32_q( W512^{qc} FFT16_p(x[32p+q]) )[d],  FFT32 = radix2 x FFT16.
// Direct global loads (no staging LDS), fft16 with upper-8-zero input,
// one LDS exchange (2 barriers total), W512^{qc} from a 4KB LDS table,
// W32^{q1} compile-time literals, chained big twiddle. 39KB LDS -> 4 blocks/CU.

#define N_FFT 131072
#define N1    512
#define N2    256
#define T_LEN 65536
#define CB    128
#define PI_F  3.14159265358979323846f
#define R2_F  0.70710678118654752f
#define C16F  0.92387953251128675613f   // cos(pi/8)
#define S16F  0.38268343236508977173f   // sin(pi/8)

typedef __attribute__((ext_vector_type(2))) __fp16 h2;
typedef __attribute__((ext_vector_type(4))) __fp16 h4;
typedef __attribute__((ext_vector_type(8))) __fp16 h8;

__device__ inline int brev9(int x) { return (int)(__brev((unsigned)x) >> 23); }

__device__ inline float2 cadd(float2 a, float2 b){ return make_float2(a.x+b.x, a.y+b.y); }
__device__ inline float2 csub(float2 a, float2 b){ return make_float2(a.x-b.x, a.y-b.y); }
__device__ inline float2 cmul(float2 a, float2 b){ return make_float2(a.x*b.x-a.y*b.y, a.x*b.y+a.y*b.x); }
// a * conj(b)
__device__ inline float2 cmulc(float2 a, float2 b){ return make_float2(a.x*b.x+a.y*b.y, a.y*b.x-a.x*b.y); }
__device__ inline float2 csq(float2 a){ return make_float2(a.x*a.x-a.y*a.y, 2.f*a.x*a.y); }
__device__ inline float2 conjf(float2 a){ return make_float2(a.x, -a.y); }
__device__ inline float2 expif(float a){ float s,c; __sincosf(a,&s,&c); return make_float2(c,s); }
__device__ inline h2 f2h(float2 v){ return __builtin_amdgcn_cvt_pkrtz(v.x, v.y); }

// specialized constant complex multiplies
__device__ inline float2 mul_mi(float2 a){ return make_float2(a.y, -a.x); }                         // * (-i)
__device__ inline float2 mul_pi(float2 a){ return make_float2(-a.y, a.x); }                         // * (+i)
__device__ inline float2 mul_w81(float2 a){ return make_float2(R2_F*(a.x+a.y), R2_F*(a.y-a.x)); }   // * ( r2,-r2)
__device__ inline float2 mul_w83(float2 a){ return make_float2(R2_F*(a.y-a.x), -R2_F*(a.x+a.y)); }  // * (-r2,-r2)
__device__ inline float2 mul_w81c(float2 a){ return make_float2(R2_F*(a.x-a.y), R2_F*(a.x+a.y)); }  // * ( r2, r2)
__device__ inline float2 mul_w83c(float2 a){ return make_float2(-R2_F*(a.x+a.y), R2_F*(a.x-a.y)); } // * (-r2, r2)

// Fused DIF double stage (h then h/2). quad (p0, p0+h/2, p0+h, p0+3h/2)
__device__ inline void dif4(float2&a0, float2&a1, float2&a2, float2&a3, float2 w1, float2 w2){
    float2 s02 = cadd(a0,a2), d02 = csub(a0,a2);
    float2 s13 = cadd(a1,a3), d13 = csub(a1,a3);
    float2 b2 = cmul(w1,d02);
    float2 t  = cmul(w1,d13);
    float2 b3 = make_float2(t.y, -t.x);          // -i*t
    a0 = cadd(s02,s13);
    a1 = cmul(w2, csub(s02,s13));
    a2 = cadd(b2,b3);
    a3 = cmul(w2, csub(b2,b3));
}

// Fused DIT double stage (h then 2h), inverse twiddles. quad (p0, p0+h, p0+2h, p0+3h)
__device__ inline void dit4i(float2&a0, float2&a1, float2&a2, float2&a3, float2 w1, float2 w2){
    float2 t1 = cmul(w1,a1), t3 = cmul(w1,a3);
    float2 u0 = cadd(a0,t1), u1 = csub(a0,t1);
    float2 u2 = cadd(a2,t3), u3 = csub(a2,t3);
    float2 s2 = cmul(w2,u2), s3 = cmul(w2,u3);
    a0 = cadd(u0,s2); a2 = csub(u0,s2);
    a1 = make_float2(u1.x - s3.y, u1.y + s3.x);  // u1 + i*s3
    a3 = make_float2(u1.x + s3.y, u1.y - s3.x);  // u1 - i*s3
}

// 4-bit bit-reversal (involution)
__device__ constexpr int BR[16] = {0,8,4,12,2,10,6,14,1,9,5,13,3,11,7,15};

// ---------------------------------------------------------------------------
// FFT-16 fully in registers, forward DIF: natural input, output v[p]=X[BR[p]].
// ---------------------------------------------------------------------------
__device__ __forceinline__ void fft16_fwd(float2 v[16]){
    { // j = 0 (trivial)
        float2 s02=cadd(v[0],v[8]),  d02=csub(v[0],v[8]);
        float2 s13=cadd(v[4],v[12]), d13=csub(v[4],v[12]);
        float2 b3 = mul_mi(d13);
        v[0]=cadd(s02,s13); v[4]=csub(s02,s13);
        v[8]=cadd(d02,b3);  v[12]=csub(d02,b3);
    }
    { // j = 1: w1=(C,-S), w2=W8^1
        float2 s02=cadd(v[1],v[9]),  d02=csub(v[1],v[9]);
        float2 s13=cadd(v[5],v[13]), d13=csub(v[5],v[13]);
        const float2 w1 = make_float2(C16F,-S16F);
        float2 b2 = cmul(w1,d02), b3 = mul_mi(cmul(w1,d13));
        v[1]=cadd(s02,s13);  v[5]=mul_w81(csub(s02,s13));
        v[9]=cadd(b2,b3);    v[13]=mul_w81(csub(b2,b3));
    }
    { // j = 2: w1=W8^1, w2=-i
        float2 s02=cadd(v[2],v[10]), d02=csub(v[2],v[10]);
        float2 s13=cadd(v[6],v[14]), d13=csub(v[6],v[14]);
        float2 b2 = mul_w81(d02), b3 = mul_mi(mul_w81(d13));
        v[2]=cadd(s02,s13);  v[6]=mul_mi(csub(s02,s13));
        v[10]=cadd(b2,b3);   v[14]=mul_mi(csub(b2,b3));
    }
    { // j = 3: w1=(S,-C), w2=W8^3
        float2 s02=cadd(v[3],v[11]), d02=csub(v[3],v[11]);
        float2 s13=cadd(v[7],v[15]), d13=csub(v[7],v[15]);
        const float2 w1 = make_float2(S16F,-C16F);
        float2 b2 = cmul(w1,d02), b3 = mul_mi(cmul(w1,d13));
        v[3]=cadd(s02,s13);  v[7]=mul_w83(csub(s02,s13));
        v[11]=cadd(b2,b3);   v[15]=mul_w83(csub(b2,b3));
    }
#pragma unroll
    for (int q=0;q<4;q++){
        float2 a0=v[4*q],a1=v[4*q+1],a2=v[4*q+2],a3=v[4*q+3];
        float2 s02=cadd(a0,a2), d02=csub(a0,a2);
        float2 s13=cadd(a1,a3), d13=csub(a1,a3);
        float2 b3 = mul_mi(d13);
        v[4*q]=cadd(s02,s13);   v[4*q+1]=csub(s02,s13);
        v[4*q+2]=cadd(d02,b3);  v[4*q+3]=csub(d02,b3);
    }
}

// Same, with v[8..15] == 0 implicit (inputs only v[0..7]); writes all 16.
__device__ __forceinline__ void fft16_fwd_z8(float2 v[16]){
    { // j = 0
        float2 a=v[0], b=v[4];
        float2 ib = mul_mi(b);
        v[0]=cadd(a,b); v[4]=csub(a,b);
        v[8]=cadd(a,ib); v[12]=csub(a,ib);
    }
    { // j = 1
        float2 a=v[1], b=v[5];
        const float2 w1 = make_float2(C16F,-S16F);
        float2 wa = cmul(w1,a), wb = mul_mi(cmul(w1,b));
        v[1]=cadd(a,b);   v[5]=mul_w81(csub(a,b));
        v[9]=cadd(wa,wb); v[13]=mul_w81(csub(wa,wb));
    }
    { // j = 2
        float2 a=v[2], b=v[6];
        float2 wa = mul_w81(a), wb = mul_mi(mul_w81(b));
        v[2]=cadd(a,b);    v[6]=mul_mi(csub(a,b));
        v[10]=cadd(wa,wb); v[14]=mul_mi(csub(wa,wb));
    }
    { // j = 3
        float2 a=v[3], b=v[7];
        const float2 w1 = make_float2(S16F,-C16F);
        float2 wa = cmul(w1,a), wb = mul_mi(cmul(w1,b));
        v[3]=cadd(a,b);    v[7]=mul_w83(csub(a,b));
        v[11]=cadd(wa,wb); v[15]=mul_w83(csub(wa,wb));
    }
#pragma unroll
    for (int q=0;q<4;q++){
        float2 a0=v[4*q],a1=v[4*q+1],a2=v[4*q+2],a3=v[4*q+3];
        float2 s02=cadd(a0,a2), d02=csub(a0,a2);
        float2 s13=cadd(a1,a3), d13=csub(a1,a3);
        float2 b3 = mul_mi(d13);
        v[4*q]=cadd(s02,s13);   v[4*q+1]=csub(s02,s13);
        v[4*q+2]=cadd(d02,b3);  v[4*q+3]=csub(d02,b3);
    }
}

// ---------------------------------------------------------------------------
// Inverse FFT-16 in registers (unnormalized, x16): input v[p]=F[BR[p]],
// natural-order output.
// ---------------------------------------------------------------------------
__device__ __forceinline__ void fft16_inv(float2 v[16]){
#pragma unroll
    for (int q=0;q<4;q++){
        float2 a0=v[4*q],a1=v[4*q+1],a2=v[4*q+2],a3=v[4*q+3];
        float2 u0=cadd(a0,a1), u1=csub(a0,a1);
        float2 u2=cadd(a2,a3), u3=csub(a2,a3);
        v[4*q]=cadd(u0,u2);   v[4*q+2]=csub(u0,u2);
        v[4*q+1]=make_float2(u1.x-u3.y, u1.y+u3.x);
        v[4*q+3]=make_float2(u1.x+u3.y, u1.y-u3.x);
    }
    { // j = 0
        float2 t1=v[4], t3=v[12];
        float2 u0=cadd(v[0],t1), u1=csub(v[0],t1);
        float2 u2=cadd(v[8],t3), u3=csub(v[8],t3);
        v[0]=cadd(u0,u2); v[8]=csub(u0,u2);
        v[4]=make_float2(u1.x-u3.y, u1.y+u3.x);
        v[12]=make_float2(u1.x+u3.y, u1.y-u3.x);
    }
    { // j = 1
        float2 t1=mul_w81c(v[5]), t3=mul_w81c(v[13]);
        float2 u0=cadd(v[1],t1), u1=csub(v[1],t1);
        float2 u2=cadd(v[9],t3), u3=csub(v[9],t3);
        const float2 w2 = make_float2(C16F,S16F);
        float2 s2=cmul(w2,u2), s3=cmul(w2,u3);
        v[1]=cadd(u0,s2); v[9]=csub(u0,s2);
        v[5]=make_float2(u1.x-s3.y, u1.y+s3.x);
        v[13]=make_float2(u1.x+s3.y, u1.y-s3.x);
    }
    { // j = 2
        float2 t1=mul_pi(v[6]), t3=mul_pi(v[14]);
        float2 u0=cadd(v[2],t1), u1=csub(v[2],t1);
        float2 u2=cadd(v[10],t3), u3=csub(v[10],t3);
        float2 s2=mul_w81c(u2), s3=mul_w81c(u3);
        v[2]=cadd(u0,s2); v[10]=csub(u0,s2);
        v[6]=make_float2(u1.x-s3.y, u1.y+s3.x);
        v[14]=make_float2(u1.x+s3.y, u1.y-s3.x);
    }
    { // j = 3
        float2 t1=mul_w83c(v[7]), t3=mul_w83c(v[15]);
        float2 u0=cadd(v[3],t1), u1=csub(v[3],t1);
        float2 u2=cadd(v[11],t3), u3=csub(v[11],t3);
        const float2 w2 = make_float2(S16F,C16F);
        float2 s2=cmul(w2,u2), s3=cmul(w2,u3);
        v[3]=cadd(u0,s2); v[11]=csub(u0,s2);
        v[7]=make_float2(u1.x-s3.y, u1.y+s3.x);
        v[15]=make_float2(u1.x+s3.y, u1.y-s3.x);
    }
}

// ---------------------------------------------------------------------------
// Forward column FFT (512-pt) over n1: 16(reg) x 32(thread) four-step.
// Block: 256 threads = 8 n2-cols x 32 q. Upper half (n1>=256) implicit zero.
//   X[c+16d] = FFT32_q( W512^{qc} FFT16_p(x[32p+q]) )[d]
//   FFT32 over q: radix-2 (q1, q1+16; parity j of d) then FFT16 over q1.
// Exchange LDS layout [n2l][c][q]: pitch 34 per c, 546 per col (bank-optimal).
// ---------------------------------------------------------------------------
#define XPC 34               // float2 pitch per c (32 q + 2 pad)
#define XPN 546              // float2 pitch per column (16*34 + 2 pad)

template<bool HALF>
__global__ __launch_bounds__(256, 4) void fwd_cols(
    const float* __restrict__ re_base, const float* __restrict__ im_base,
    long long row_stride, void* __restrict__ dstv)
{
    __shared__ __align__(16) float2 s[8 * XPN + 32 * 17];  // 39,296 B
    const int tid = threadIdx.x;
    const int tile = blockIdx.x, row = blockIdx.y;
    const int n2base = tile * 8;
    float2* tab = s + 8 * XPN;

    { // W512^{qc} table: 512 entries, pitch 17 (broadcast-read friendly)
        int q = tid >> 4, c = tid & 15;
        tab[q * 17 + c]        = expif((float)(q * c) * (-2.f * PI_F / 512.f));
        tab[(q + 16) * 17 + c] = expif((float)((q + 16) * c) * (-2.f * PI_F / 512.f));
    }
    __syncthreads();

    const int n2l = tid & 7, q = tid >> 3;        // q in [0,32)
    const float* rp = re_base + (long long)row * row_stride;
    const float* ip = im_base ? (im_base + (long long)row * row_stride) : nullptr;

    // ---- phase A: direct loads (n1 = 32p + q < 256 -> p < 8), FFT16 over p
    float2 v[16];
    if (ip) {
#pragma unroll
        for (int p = 0; p < 8; p++) {
            int g = (32 * p + q) * N2 + n2base + n2l;
            v[p] = make_float2(rp[g], ip[g]);
        }
    } else {
#pragma unroll
        for (int p = 0; p < 8; p++) {
            int g = (32 * p + q) * N2 + n2base + n2l;
            v[p] = make_float2(rp[g], 0.f);
        }
    }
    fft16_fwd_z8(v);                              // v[BR[c]] = F_q[c]

    // twiddle W512^{qc} from table, write exchange [n2l][c][q]
#pragma unroll
    for (int c = 1; c < 16; c++) v[BR[c]] = cmul(v[BR[c]], tab[q * 17 + c]);
#pragma unroll
    for (int c = 0; c < 16; c++) s[n2l * XPN + c * XPC + q] = v[BR[c]];
    __syncthreads();

    // ---- phase B: thread (n2l, c, j): radix-2 over q0, FFT16 over q1
    const int sI = tid >> 3;                      // [0,32)
    const int cc = sI & 15, jj = sI >> 4;         // jj wave-uniform
    const float4* z4 = (const float4*)(s + n2l * XPN + cc * XPC);
    float2 b[16];
    if (jj == 0) {
#pragma unroll
        for (int k = 0; k < 8; k++) {
            float4 A = z4[k], B = z4[k + 8];
            b[2*k]   = make_float2(A.x + B.x, A.y + B.y);
            b[2*k+1] = make_float2(A.z + B.z, A.w + B.w);
        }
    } else {
        // W32^{q1} = (cos(pi q1/16), -sin(pi q1/16)), compile-time
        constexpr float CT[16] = {
            1.f, 0.98078528040323044913f, 0.92387953251128675613f, 0.83146961230254523708f,
            0.70710678118654752440f, 0.55557023301960222474f, 0.38268343236508977173f,
            0.19509032201612826785f, 0.f, -0.19509032201612826785f, -0.38268343236508977173f,
            -0.55557023301960222474f, -0.70710678118654752440f, -0.83146961230254523708f,
            -0.92387953251128675613f, -0.98078528040323044913f };
        constexpr float ST[16] = {
            0.f, -0.19509032201612826785f, -0.38268343236508977173f, -0.55557023301960222474f,
            -0.70710678118654752440f, -0.83146961230254523708f, -0.92387953251128675613f,
            -0.98078528040323044913f, -1.f, -0.98078528040323044913f, -0.92387953251128675613f,
            -0.83146961230254523708f, -0.70710678118654752440f, -0.55557023301960222474f,
            -0.38268343236508977173f, -0.19509032201612826785f };
#pragma unroll
        for (int k = 0; k < 8; k++) {
            float4 A = z4[k], B = z4[k + 8];
            float2 d0 = make_float2(A.x - B.x, A.y - B.y);
            float2 d1 = make_float2(A.z - B.z, A.w - B.w);
            b[2*k]   = (k == 0) ? d0 : cmul(d0, make_float2(CT[2*k], ST[2*k]));
            b[2*k+1] = cmul(d1, make_float2(CT[2*k+1], ST[2*k+1]));
        }
    }
    fft16_fwd(b);                                 // b[BR[m]] = G[2m+jj]

    // ---- big twiddle W_N^{n2*k1} (chained), store at k1 = cc + 32m + 16jj
    const int n2 = n2base + n2l;
    const float th = -2.f * PI_F / (float)N_FFT;
    float2 w   = expif(th * (float)(n2 * (cc + 16 * jj)));
    float2 stp = expif(th * (float)(32 * n2));
#pragma unroll
    for (int m = 0; m < 16; m++) {
        float2 rv = cmul(b[BR[m]], w);
        int k1 = cc + 32 * m + 16 * jj;
        if (HALF) {
            h2* drow = (h2*)dstv + (size_t)row * N_FFT;
            drow[(size_t)k1 * N2 + n2] = f2h(rv);
        } else {
            float2* drow = (float2*)dstv + (size_t)row * N_FFT;
            drow[(size_t)k1 * N2 + n2] = rv;
        }
        if (m < 15) w = cmul(w, stp);
    }
}

// ---------------------------------------------------------------------------
// Row-kernel LDS pitch: 18 float2 per 16-point group
// ---------------------------------------------------------------------------
#define RPITCH 18

// ---------------------------------------------------------------------------
// Filter row FFTs: 256-pt forward via 16x16 four-step, FFT-16 in registers.
// Output layout matches mid_rows' register permutation:
//   Ghat[row*256 + 16*t + p] = X[t + 16*BR[p]]
// ---------------------------------------------------------------------------
__global__ __launch_bounds__(128) void fwd_rows_g(float2* __restrict__ G)
{
    __shared__ __align__(16) float2 s[8 * 16 * RPITCH + 16 * RPITCH];
    const int tid = threadIdx.x;
    const int t = tid & 15, rl = tid >> 4;
    const long long row = (long long)blockIdx.x * 8 + rl;
    float2* tab = s + 8 * 16 * RPITCH;

    { // W256^{b*c} table, pitch 18; 128 threads cover 256 entries
        int b0 = tid >> 4, c0 = tid & 15;
        tab[b0 * RPITCH + c0] = expif((float)(b0 * c0) * (-2.f * PI_F / 256.f));
        int e = tid + 128, b1 = e >> 4, c1 = e & 15;
        tab[b1 * RPITCH + c1] = expif((float)(b1 * c1) * (-2.f * PI_F / 256.f));
    }
    __syncthreads();

    const float2* gp = G + (size_t)row * N2 + t;
    float2 v[16];
#pragma unroll
    for (int a = 0; a < 16; a++) v[a] = gp[16 * a];

    fft16_fwd(v);
#pragma unroll
    for (int p = 1; p < 16; p++) v[p] = cmul(v[p], tab[t * RPITCH + BR[p]]);

    float2* rS = s + rl * (16 * RPITCH);
    float4* rS4 = (float4*)rS;
#pragma unroll
    for (int k = 0; k < 8; k++) {
        float2 e = v[BR[2*k]], o = v[BR[2*k] + 8];
        rS4[(t * RPITCH + 2*k) >> 1] = make_float4(e.x, e.y, o.x, o.y);
    }
    asm volatile("s_waitcnt lgkmcnt(0)" ::: "memory");
#pragma unroll
    for (int b = 0; b < 16; b++) v[b] = rS[b * RPITCH + t];

    fft16_fwd(v);

    float4* o4 = (float4*)(G + (size_t)row * N2 + 16 * t);
#pragma unroll
    for (int m = 0; m < 8; m++)
        o4[m] = make_float4(v[2*m].x, v[2*m].y, v[2*m+1].x, v[2*m+1].y);
}

// ---------------------------------------------------------------------------
// Fused mid: fwd row FFT -> x Ghat -> inv row FFT -> conj big twiddle.
// 16x16 four-step, FFT-16 in registers; intra-wave exchange, one barrier.
// ---------------------------------------------------------------------------
__global__ __launch_bounds__(256, 4) void mid_rows(
    h2* __restrict__ buf, const float2* __restrict__ Gh)
{
    __shared__ __align__(16) float2 s[16 * 16 * RPITCH + 16 * RPITCH];
    const int tid = threadIdx.x;
    const int t = tid & 15, rl = tid >> 4;
    const long long row = (long long)blockIdx.x * 16 + rl;
    const int k1 = (int)(row & (N1 - 1));
    float2* tab = s + 16 * 16 * RPITCH;

    { // W256^{b*c} table
        int b = tid >> 4, c = tid & 15;
        tab[b * RPITCH + c] = expif((float)(b * c) * (-2.f * PI_F / 256.f));
    }
    __syncthreads();                              // the only barrier

    h2* bp = buf + ((size_t)row * N2 + t);
    float2 v[16];
#pragma unroll
    for (int a = 0; a < 16; a++) {
        h2 h = bp[16 * a];
        v[a] = make_float2((float)h.x, (float)h.y);
    }

    fft16_fwd(v);
#pragma unroll
    for (int p = 1; p < 16; p++) v[p] = cmul(v[p], tab[t * RPITCH + BR[p]]);

    float2* rS = s + rl * (16 * RPITCH);
    float4* rS4 = (float4*)rS;
#pragma unroll
    for (int k = 0; k < 8; k++) {
        float2 e = v[BR[2*k]], o = v[BR[2*k] + 8];
        rS4[(t * RPITCH + 2*k) >> 1] = make_float4(e.x, e.y, o.x, o.y);
    }

    const float4* g4 = (const float4*)(Gh + ((size_t)k1 * N2 + 16 * t));
    float4 g[8];
#pragma unroll
    for (int m = 0; m < 8; m++) g[m] = g4[m];

    asm volatile("s_waitcnt lgkmcnt(0)" ::: "memory");
#pragma unroll
    for (int b = 0; b < 16; b++) v[b] = rS[b * RPITCH + t];

    fft16_fwd(v);

#pragma unroll
    for (int m = 0; m < 8; m++) {
        v[2*m]   = cmul(v[2*m],   make_float2(g[m].x, g[m].y));
        v[2*m+1] = cmul(v[2*m+1], make_float2(g[m].z, g[m].w));
    }

    fft16_inv(v);
#pragma unroll
    for (int b = 1; b < 16; b++) v[b] = cmulc(v[b], tab[b * RPITCH + t]);

#pragma unroll
    for (int m = 0; m < 8; m++)
        rS4[(t * RPITCH + 2*m) >> 1] = make_float4(v[2*m].x, v[2*m].y, v[2*m+1].x, v[2*m+1].y);
    asm volatile("s_waitcnt lgkmcnt(0)" ::: "memory");
#pragma unroll
    for (int c = 0; c < 16; c++) v[BR[c]] = rS[c * RPITCH + t];

    fft16_inv(v);

    {
        const float th = 2.f * PI_F / (float)N_FFT;
        float2 w = expif((float)(k1 * t) * th);
        const float2 stp = expif((float)(16 * k1) * th);
#pragma unroll
        for (int a = 0; a < 16; a++) {
            float2 r = cmul(v[a], w);
            bp[16 * a] = f2h(r);
            if (a < 15) w = cmul(w, stp);
        }
    }
}

// ---------------------------------------------------------------------------
// Inverse column FFT (512-pt DIT, brev load) over k1, scale, keep n1<256.
// ---------------------------------------------------------------------------
__global__ __launch_bounds__(512, 4) void inv_cols(
    const h2* __restrict__ src, float* __restrict__ out)
{
    __shared__ float4 s4[N1 * 16 / 2];            // 64 KB
    float2* s = (float2*)s4;
    const int tile = blockIdx.x, row = blockIdx.y, tid = threadIdx.x;
    const int n2base = tile * 16;
    const h2* srow = src + (size_t)row * N_FFT;
    const int cp = tid & 7, r8 = tid >> 3;        // r8 in [0,64)

#pragma unroll
    for (int i = 0; i < 8; i++) {
        int k1 = r8 + 64 * i;
        h4 v = *((const h4*)(srow + (size_t)k1 * N2 + n2base + 2 * cp));
        int p = brev9(k1);
        s4[p * 8 + cp] = make_float4((float)v.x, (float)v.y, (float)v.z, (float)v.w);
    }
    __syncthreads();

    const int c = tid & 15, r = tid >> 4;         // r in [0,32)

    const float2 w1c = make_float2(0.f, 1.f);     // conj(W_4^1) = i
    const float2 w2c = make_float2(R2_F, R2_F);   // conj(W_8^1)
    const float2 one = make_float2(1.f, 0.f);
#pragma unroll
    for (int o = 0; o < 2; o++) {
        int base = 8 * (r + 32 * o);
        float2 v[8];
#pragma unroll
        for (int m = 0; m < 8; m++) v[m] = s[(base + m) * 16 + c];
#pragma unroll
        for (int m = 0; m < 8; m += 2) {
            float2 a = v[m], b = v[m + 1];
            v[m] = cadd(a, b); v[m + 1] = csub(a, b);
        }
        dit4i(v[0], v[2], v[4], v[6], one, one);
        dit4i(v[1], v[3], v[5], v[7], w1c, w2c);
#pragma unroll
        for (int m = 0; m < 8; m++) s[(base + m) * 16 + c] = v[m];
    }
    __syncthreads();

    {
        float2 w2 = expif((float)(r & 7) * (PI_F / 16.f));
        float2 w1 = csq(w2);
#pragma unroll
        for (int qq = 0; qq < 4; qq++) {
            int g = (r >> 3) + 4 * qq;
            int p0 = g * 32 + (r & 7);
            float2 a0 = s[p0*16+c], a1 = s[(p0+8)*16+c], a2 = s[(p0+16)*16+c], a3 = s[(p0+24)*16+c];
            dit4i(a0, a1, a2, a3, w1, w2);
            s[p0*16+c] = a0; s[(p0+8)*16+c] = a1; s[(p0+16)*16+c] = a2; s[(p0+24)*16+c] = a3;
        }
    }
    __syncthreads();
    {
        float2 w2 = expif((float)r * (PI_F / 64.f));
        float2 w1 = csq(w2);
#pragma unroll
        for (int qq = 0; qq < 4; qq++) {
            int p0 = qq * 128 + r;
            float2 a0 = s[p0*16+c], a1 = s[(p0+32)*16+c], a2 = s[(p0+64)*16+c], a3 = s[(p0+96)*16+c];
            dit4i(a0, a1, a2, a3, w1, w2);
            s[p0*16+c] = a0; s[(p0+32)*16+c] = a1; s[(p0+64)*16+c] = a2; s[(p0+96)*16+c] = a3;
        }
    }
    __syncthreads();
    {
        float2 w2 = expif((float)r * (PI_F / 256.f));
        const float2 stp = make_float2(0.92387953251f, 0.38268343236f);
#pragma unroll
        for (int qq = 0; qq < 4; qq++) {
            int j = r + 32 * qq;
            float2 w1 = csq(w2);
            float2 a0 = s[j*16+c], a1 = s[(j+128)*16+c], a2 = s[(j+256)*16+c], a3 = s[(j+384)*16+c];
            dit4i(a0, a1, a2, a3, w1, w2);
            s[j*16+c] = a0; s[(j+128)*16+c] = a1; s[(j+256)*16+c] = a2; s[(j+384)*16+c] = a3;
            w2 = cmul(w2, stp);
        }
    }
    __syncthreads();

    const float scale = 1.0f / (float)N_FFT;
    float* out0 = out + (size_t)(2 * row) * T_LEN;
    float* out1 = out + (size_t)(2 * row + 1) * T_LEN;
#pragma unroll
    for (int i = 0; i < 4; i++) {
        int p = r8 + 64 * i;                      // p < 256
        float4 q = s4[p * 8 + cp];
        int n = p * N2 + n2base + 2 * cp;
        *(float2*)(out0 + n) = make_float2(q.x * scale, q.z * scale);
        *(float2*)(out1 + n) = make_float2(q.y * scale, q.w * scale);
    }
}

extern "C" void kernel_launch(void* const* d_in, const int* in_sizes, int n_in,
                              void* d_out, int out_size, void* d_ws, size_t ws_size,
                              hipStream_t stream) {
    const float* x    = (const float*)d_in[0];
    const float* filt = (const float*)d_in[1];
    float* out = (float*)d_out;

    h2* buf = (h2*)d_ws;                                                        // 67 MB
    float2* G = (float2*)((char*)d_ws + (size_t)CB * N_FFT * sizeof(h2));       // 1 MB

    fwd_cols<false><<<dim3(32, 1), 256, 0, stream>>>(filt, nullptr, 0LL, (void*)G);
    fwd_rows_g<<<N1 / 8, 128, 0, stream>>>(G);
    fwd_cols<true><<<dim3(32, CB), 256, 0, stream>>>(x, x + T_LEN, (long long)(2 * T_LEN), (void*)buf);
    mid_rows<<<(CB * N1) / 16, 256, 0, stream>>>(buf, G);
    inv_cols<<<dim3(16, CB), 512, 0, stream>>>(buf, out);
}

// Round 4
// 224.225 us; speedup vs baseline: 1.0886x; 1.0886x over previous
//
#include <hip/hip_runtime.h>

// Causal FIR conv via FFT (n_fft = 131072), four-step N = 512 x 256,
// transpose-free, batch-packed (2 real rows -> 1 complex row).
// v8 (resubmit; previous bench was an infra failure):
// fwd_cols = 32(reg) x 16(thread) four-step with 64B-coalesced access:
//   n1 = 16p + q; FFT32 over p (upper half zero => 2x FFT16: on x and x*W32^p),
//   twiddle W512^{qr} (chained, no LDS table), 2-round r-half exchange
//   (37 KB LDS -> 4 blocks/CU), FFT16 over q, chained big twiddle, h2 store.
//   Lanes: n2l = tid&15 fast => 16x4B = 64B runs on loads AND stores (1x fetch).
//   Barriers are lgkmcnt-only (global stores not drained).

#define N_FFT 131072
#define N1    512
#define N2    256
#define T_LEN 65536
#define CB    128
#define PI_F  3.14159265358979323846f
#define R2_F  0.70710678118654752f
#define C16F  0.92387953251128675613f   // cos(pi/8)
#define S16F  0.38268343236508977173f   // sin(pi/8)

typedef __attribute__((ext_vector_type(2))) __fp16 h2;
typedef __attribute__((ext_vector_type(4))) __fp16 h4;
typedef __attribute__((ext_vector_type(8))) __fp16 h8;

__device__ inline int brev9(int x) { return (int)(__brev((unsigned)x) >> 23); }

__device__ inline float2 cadd(float2 a, float2 b){ return make_float2(a.x+b.x, a.y+b.y); }
__device__ inline float2 csub(float2 a, float2 b){ return make_float2(a.x-b.x, a.y-b.y); }
__device__ inline float2 cmul(float2 a, float2 b){ return make_float2(a.x*b.x-a.y*b.y, a.x*b.y+a.y*b.x); }
// a * conj(b)
__device__ inline float2 cmulc(float2 a, float2 b){ return make_float2(a.x*b.x+a.y*b.y, a.y*b.x-a.x*b.y); }
__device__ inline float2 csq(float2 a){ return make_float2(a.x*a.x-a.y*a.y, 2.f*a.x*a.y); }
__device__ inline float2 conjf(float2 a){ return make_float2(a.x, -a.y); }
__device__ inline float2 expif(float a){ float s,c; __sincosf(a,&s,&c); return make_float2(c,s); }
__device__ inline h2 f2h(float2 v){ return __builtin_amdgcn_cvt_pkrtz(v.x, v.y); }

// specialized constant complex multiplies
__device__ inline float2 mul_mi(float2 a){ return make_float2(a.y, -a.x); }                         // * (-i)
__device__ inline float2 mul_pi(float2 a){ return make_float2(-a.y, a.x); }                         // * (+i)
__device__ inline float2 mul_w81(float2 a){ return make_float2(R2_F*(a.x+a.y), R2_F*(a.y-a.x)); }   // * ( r2,-r2)
__device__ inline float2 mul_w83(float2 a){ return make_float2(R2_F*(a.y-a.x), -R2_F*(a.x+a.y)); }  // * (-r2,-r2)
__device__ inline float2 mul_w81c(float2 a){ return make_float2(R2_F*(a.x-a.y), R2_F*(a.x+a.y)); }  // * ( r2, r2)
__device__ inline float2 mul_w83c(float2 a){ return make_float2(-R2_F*(a.x+a.y), R2_F*(a.x-a.y)); } // * (-r2, r2)

// lgkm-only block barrier: don't drain vmcnt (global stores stay in flight)
__device__ __forceinline__ void lgkm_barrier(){
    asm volatile("s_waitcnt lgkmcnt(0)" ::: "memory");
    __builtin_amdgcn_s_barrier();
    __builtin_amdgcn_sched_barrier(0);
}

// Fused DIF double stage (h then h/2). quad (p0, p0+h/2, p0+h, p0+3h/2)
__device__ inline void dif4(float2&a0, float2&a1, float2&a2, float2&a3, float2 w1, float2 w2){
    float2 s02 = cadd(a0,a2), d02 = csub(a0,a2);
    float2 s13 = cadd(a1,a3), d13 = csub(a1,a3);
    float2 b2 = cmul(w1,d02);
    float2 t  = cmul(w1,d13);
    float2 b3 = make_float2(t.y, -t.x);          // -i*t
    a0 = cadd(s02,s13);
    a1 = cmul(w2, csub(s02,s13));
    a2 = cadd(b2,b3);
    a3 = cmul(w2, csub(b2,b3));
}

// Fused DIT double stage (h then 2h), inverse twiddles. quad (p0, p0+h, p0+2h, p0+3h)
__device__ inline void dit4i(float2&a0, float2&a1, float2&a2, float2&a3, float2 w1, float2 w2){
    float2 t1 = cmul(w1,a1), t3 = cmul(w1,a3);
    float2 u0 = cadd(a0,t1), u1 = csub(a0,t1);
    float2 u2 = cadd(a2,t3), u3 = csub(a2,t3);
    float2 s2 = cmul(w2,u2), s3 = cmul(w2,u3);
    a0 = cadd(u0,s2); a2 = csub(u0,s2);
    a1 = make_float2(u1.x - s3.y, u1.y + s3.x);  // u1 + i*s3
    a3 = make_float2(u1.x + s3.y, u1.y - s3.x);  // u1 - i*s3
}

// 4-bit bit-reversal (involution)
__device__ constexpr int BR[16] = {0,8,4,12,2,10,6,14,1,9,5,13,3,11,7,15};

// ---------------------------------------------------------------------------
// FFT-16 fully in registers, forward DIF: natural input, output v[BR[s]]=X[s].
// ---------------------------------------------------------------------------
__device__ __forceinline__ void fft16_fwd(float2 v[16]){
    { // j = 0 (trivial)
        float2 s02=cadd(v[0],v[8]),  d02=csub(v[0],v[8]);
        float2 s13=cadd(v[4],v[12]), d13=csub(v[4],v[12]);
        float2 b3 = mul_mi(d13);
        v[0]=cadd(s02,s13); v[4]=csub(s02,s13);
        v[8]=cadd(d02,b3);  v[12]=csub(d02,b3);
    }
    { // j = 1: w1=(C,-S), w2=W8^1
        float2 s02=cadd(v[1],v[9]),  d02=csub(v[1],v[9]);
        float2 s13=cadd(v[5],v[13]), d13=csub(v[5],v[13]);
        const float2 w1 = make_float2(C16F,-S16F);
        float2 b2 = cmul(w1,d02), b3 = mul_mi(cmul(w1,d13));
        v[1]=cadd(s02,s13);  v[5]=mul_w81(csub(s02,s13));
        v[9]=cadd(b2,b3);    v[13]=mul_w81(csub(b2,b3));
    }
    { // j = 2: w1=W8^1, w2=-i
        float2 s02=cadd(v[2],v[10]), d02=csub(v[2],v[10]);
        float2 s13=cadd(v[6],v[14]), d13=csub(v[6],v[14]);
        float2 b2 = mul_w81(d02), b3 = mul_mi(mul_w81(d13));
        v[2]=cadd(s02,s13);  v[6]=mul_mi(csub(s02,s13));
        v[10]=cadd(b2,b3);   v[14]=mul_mi(csub(b2,b3));
    }
    { // j = 3: w1=(S,-C), w2=W8^3
        float2 s02=cadd(v[3],v[11]), d02=csub(v[3],v[11]);
        float2 s13=cadd(v[7],v[15]), d13=csub(v[7],v[15]);
        const float2 w1 = make_float2(S16F,-C16F);
        float2 b2 = cmul(w1,d02), b3 = mul_mi(cmul(w1,d13));
        v[3]=cadd(s02,s13);  v[7]=mul_w83(csub(s02,s13));
        v[11]=cadd(b2,b3);   v[15]=mul_w83(csub(b2,b3));
    }
#pragma unroll
    for (int q=0;q<4;q++){
        float2 a0=v[4*q],a1=v[4*q+1],a2=v[4*q+2],a3=v[4*q+3];
        float2 s02=cadd(a0,a2), d02=csub(a0,a2);
        float2 s13=cadd(a1,a3), d13=csub(a1,a3);
        float2 b3 = mul_mi(d13);
        v[4*q]=cadd(s02,s13);   v[4*q+1]=csub(s02,s13);
        v[4*q+2]=cadd(d02,b3);  v[4*q+3]=csub(d02,b3);
    }
}

// ---------------------------------------------------------------------------
// Inverse FFT-16 in registers (unnormalized, x16): input v[BR[d]]=F[d],
// natural-order output.
// ---------------------------------------------------------------------------
__device__ __forceinline__ void fft16_inv(float2 v[16]){
#pragma unroll
    for (int q=0;q<4;q++){
        float2 a0=v[4*q],a1=v[4*q+1],a2=v[4*q+2],a3=v[4*q+3];
        float2 u0=cadd(a0,a1), u1=csub(a0,a1);
        float2 u2=cadd(a2,a3), u3=csub(a2,a3);
        v[4*q]=cadd(u0,u2);   v[4*q+2]=csub(u0,u2);
        v[4*q+1]=make_float2(u1.x-u3.y, u1.y+u3.x);
        v[4*q+3]=make_float2(u1.x+u3.y, u1.y-u3.x);
    }
    { // j = 0
        float2 t1=v[4], t3=v[12];
        float2 u0=cadd(v[0],t1), u1=csub(v[0],t1);
        float2 u2=cadd(v[8],t3), u3=csub(v[8],t3);
        v[0]=cadd(u0,u2); v[8]=csub(u0,u2);
        v[4]=make_float2(u1.x-u3.y, u1.y+u3.x);
        v[12]=make_float2(u1.x+u3.y, u1.y-u3.x);
    }
    { // j = 1
        float2 t1=mul_w81c(v[5]), t3=mul_w81c(v[13]);
        float2 u0=cadd(v[1],t1), u1=csub(v[1],t1);
        float2 u2=cadd(v[9],t3), u3=csub(v[9],t3);
        const float2 w2 = make_float2(C16F,S16F);
        float2 s2=cmul(w2,u2), s3=cmul(w2,u3);
        v[1]=cadd(u0,s2); v[9]=csub(u0,s2);
        v[5]=make_float2(u1.x-s3.y, u1.y+s3.x);
        v[13]=make_float2(u1.x+s3.y, u1.y-s3.x);
    }
    { // j = 2
        float2 t1=mul_pi(v[6]), t3=mul_pi(v[14]);
        float2 u0=cadd(v[2],t1), u1=csub(v[2],t1);
        float2 u2=cadd(v[10],t3), u3=csub(v[10],t3);
        float2 s2=mul_w81c(u2), s3=mul_w81c(u3);
        v[2]=cadd(u0,s2); v[10]=csub(u0,s2);
        v[6]=make_float2(u1.x-s3.y, u1.y+s3.x);
        v[14]=make_float2(u1.x+s3.y, u1.y-s3.x);
    }
    { // j = 3
        float2 t1=mul_w83c(v[7]), t3=mul_w83c(v[15]);
        float2 u0=cadd(v[3],t1), u1=csub(v[3],t1);
        float2 u2=cadd(v[11],t3), u3=csub(v[11],t3);
        const float2 w2 = make_float2(S16F,C16F);
        float2 s2=cmul(w2,u2), s3=cmul(w2,u3);
        v[3]=cadd(u0,s2); v[11]=csub(u0,s2);
        v[7]=make_float2(u1.x-s3.y, u1.y+s3.x);
        v[15]=make_float2(u1.x+s3.y, u1.y-s3.x);
    }
}

// ---------------------------------------------------------------------------
// Forward column FFT (512-pt) over n1: 32(reg) x 16(thread) four-step.
// Block: 256 threads = 16 n2-cols (fast) x 16 q. n1 = 16p + q; input nonzero
// only n1 < 256 <=> p < 16. FFT32 over p with zero half = 2x FFT16:
//   F_q[2t] = FFT16(x)[t], F_q[2t+1] = FFT16(x * W32^p)[t].
// X[r + 32 s] = FFT16_q( W512^{qr} F_q[r] )[s]; store k1 = r + 32 s.
// Exchange in 2 rounds over r-halves: ex[n2l][rl(16)][q(16)], pitches 290/18/1.
// ---------------------------------------------------------------------------
template<bool HALF>
__global__ __launch_bounds__(256, 4) void fwd_cols(
    const float* __restrict__ re_base, const float* __restrict__ im_base,
    long long row_stride, void* __restrict__ dstv)
{
    __shared__ __align__(16) float2 s[16 * 290];   // 37,120 B
    const int tid = threadIdx.x;
    const int tile = blockIdx.x, row = blockIdx.y;
    const int n2base = tile * 16;
    const int n2l = tid & 15, q = tid >> 4;        // both in [0,16)
    const int n2 = n2base + n2l;

    const float* rp = re_base + (long long)row * row_stride;
    const float* ip = im_base ? (im_base + (long long)row * row_stride) : nullptr;

    // ---- phase A: loads (64B runs), two FFT16s
    float2 vE[16], vO[16];
    if (ip) {
#pragma unroll
        for (int p = 0; p < 16; p++) {
            int g = (16 * p + q) * N2 + n2;
            vE[p] = make_float2(rp[g], ip[g]);
        }
    } else {
#pragma unroll
        for (int p = 0; p < 16; p++) {
            int g = (16 * p + q) * N2 + n2;
            vE[p] = make_float2(rp[g], 0.f);
        }
    }
    { // vO = x * W32^p, W32^p = (cos(pi p/16), -sin(pi p/16)) compile-time
        constexpr float WC[16] = {
            1.f, 0.98078528040323044913f, 0.92387953251128675613f, 0.83146961230254523708f,
            0.70710678118654752440f, 0.55557023301960222474f, 0.38268343236508977173f,
            0.19509032201612826785f, 0.f, -0.19509032201612826785f, -0.38268343236508977173f,
            -0.55557023301960222474f, -0.70710678118654752440f, -0.83146961230254523708f,
            -0.92387953251128675613f, -0.98078528040323044913f };
        constexpr float WS[16] = {
            0.f, -0.19509032201612826785f, -0.38268343236508977173f, -0.55557023301960222474f,
            -0.70710678118654752440f, -0.83146961230254523708f, -0.92387953251128675613f,
            -0.98078528040323044913f, -1.f, -0.98078528040323044913f, -0.92387953251128675613f,
            -0.83146961230254523708f, -0.70710678118654752440f, -0.55557023301960222474f,
            -0.38268343236508977173f, -0.19509032201612826785f };
        vO[0] = vE[0];
#pragma unroll
        for (int p = 1; p < 16; p++) vO[p] = cmul(vE[p], make_float2(WC[p], WS[p]));
    }
    fft16_fwd(vE);                                 // vE[BR[t]] = F_q[2t]
    fft16_fwd(vO);                                 // vO[BR[t]] = F_q[2t+1]

    // ---- exchange twiddle chain: w = W512^{q*r}, u = W512^{q}
    const float2 u = expif((float)q * (-2.f * PI_F / 512.f));
    float2 w = make_float2(1.f, 0.f);
    const int exbase = n2l * 290;
    const float thN = -2.f * PI_F / (float)N_FFT;
    const float2 stpN = expif(thN * (float)(32 * n2));

#pragma unroll
    for (int h = 0; h < 2; h++) {
        // write round h: r = 16h + rl, rl in [0,16); w chained = W512^{qr}
#pragma unroll
        for (int t = 0; t < 8; t++) {
            int tt = t + 8 * h;                    // r = 2*tt, 2*tt+1
            int rl = 2 * t;
            s[exbase + rl * 18 + q]       = cmul(vE[BR[tt]], w);  w = cmul(w, u);
            s[exbase + (rl + 1) * 18 + q] = cmul(vO[BR[tt]], w);  w = cmul(w, u);
        }
        lgkm_barrier();

        // read round h: this thread owns r' = 16h + q
        float2 b[16];
        {
            const float4* z4 = (const float4*)(s + exbase + q * 18);
#pragma unroll
            for (int j = 0; j < 8; j++) {
                float4 A = z4[j];
                b[2*j]   = make_float2(A.x, A.y);
                b[2*j+1] = make_float2(A.z, A.w);
            }
        }
        fft16_fwd(b);                              // b[BR[s]] = X[r' + 32 s]

        // big twiddle W_N^{n2*k1}, k1 = r' + 32 m (chained), store
        const int rpr = 16 * h + q;
        float2 wb = expif(thN * (float)(n2 * rpr));
#pragma unroll
        for (int m = 0; m < 16; m++) {
            float2 rv = cmul(b[BR[m]], wb);
            int k1 = rpr + 32 * m;
            if (HALF) {
                h2* drow = (h2*)dstv + (size_t)row * N_FFT;
                drow[(size_t)k1 * N2 + n2] = f2h(rv);
            } else {
                float2* drow = (float2*)dstv + (size_t)row * N_FFT;
                drow[(size_t)k1 * N2 + n2] = rv;
            }
            if (m < 15) wb = cmul(wb, stpN);
        }
        if (h == 0) lgkm_barrier();                // reads done -> round 1 may overwrite
    }
}

// ---------------------------------------------------------------------------
// Row-kernel LDS pitch: 18 float2 per 16-point group
// ---------------------------------------------------------------------------
#define RPITCH 18

// ---------------------------------------------------------------------------
// Filter row FFTs: 256-pt forward via 16x16 four-step, FFT-16 in registers.
// Output layout matches mid_rows' register permutation:
//   Ghat[row*256 + 16*t + p] = X[t + 16*BR[p]]
// ---------------------------------------------------------------------------
__global__ __launch_bounds__(128) void fwd_rows_g(float2* __restrict__ G)
{
    __shared__ __align__(16) float2 s[8 * 16 * RPITCH + 16 * RPITCH];
    const int tid = threadIdx.x;
    const int t = tid & 15, rl = tid >> 4;
    const long long row = (long long)blockIdx.x * 8 + rl;
    float2* tab = s + 8 * 16 * RPITCH;

    { // W256^{b*c} table, pitch 18; 128 threads cover 256 entries
        int b0 = tid >> 4, c0 = tid & 15;
        tab[b0 * RPITCH + c0] = expif((float)(b0 * c0) * (-2.f * PI_F / 256.f));
        int e = tid + 128, b1 = e >> 4, c1 = e & 15;
        tab[b1 * RPITCH + c1] = expif((float)(b1 * c1) * (-2.f * PI_F / 256.f));
    }
    __syncthreads();

    const float2* gp = G + (size_t)row * N2 + t;
    float2 v[16];
#pragma unroll
    for (int a = 0; a < 16; a++) v[a] = gp[16 * a];

    fft16_fwd(v);
#pragma unroll
    for (int p = 1; p < 16; p++) v[p] = cmul(v[p], tab[t * RPITCH + BR[p]]);

    float2* rS = s + rl * (16 * RPITCH);
    float4* rS4 = (float4*)rS;
#pragma unroll
    for (int k = 0; k < 8; k++) {
        float2 e = v[BR[2*k]], o = v[BR[2*k] + 8];
        rS4[(t * RPITCH + 2*k) >> 1] = make_float4(e.x, e.y, o.x, o.y);
    }
    asm volatile("s_waitcnt lgkmcnt(0)" ::: "memory");
#pragma unroll
    for (int b = 0; b < 16; b++) v[b] = rS[b * RPITCH + t];

    fft16_fwd(v);

    float4* o4 = (float4*)(G + (size_t)row * N2 + 16 * t);
#pragma unroll
    for (int m = 0; m < 8; m++)
        o4[m] = make_float4(v[2*m].x, v[2*m].y, v[2*m+1].x, v[2*m+1].y);
}

// ---------------------------------------------------------------------------
// Fused mid: fwd row FFT -> x Ghat -> inv row FFT -> conj big twiddle.
// 16x16 four-step, FFT-16 in registers; intra-wave exchange, one barrier.
// ---------------------------------------------------------------------------
__global__ __launch_bounds__(256, 4) void mid_rows(
    h2* __restrict__ buf, const float2* __restrict__ Gh)
{
    __shared__ __align__(16) float2 s[16 * 16 * RPITCH + 16 * RPITCH];
    const int tid = threadIdx.x;
    const int t = tid & 15, rl = tid >> 4;
    const long long row = (long long)blockIdx.x * 16 + rl;
    const int k1 = (int)(row & (N1 - 1));
    float2* tab = s + 16 * 16 * RPITCH;

    { // W256^{b*c} table
        int b = tid >> 4, c = tid & 15;
        tab[b * RPITCH + c] = expif((float)(b * c) * (-2.f * PI_F / 256.f));
    }
    __syncthreads();                              // the only barrier

    h2* bp = buf + ((size_t)row * N2 + t);
    float2 v[16];
#pragma unroll
    for (int a = 0; a < 16; a++) {
        h2 h = bp[16 * a];
        v[a] = make_float2((float)h.x, (float)h.y);
    }

    fft16_fwd(v);
#pragma unroll
    for (int p = 1; p < 16; p++) v[p] = cmul(v[p], tab[t * RPITCH + BR[p]]);

    float2* rS = s + rl * (16 * RPITCH);
    float4* rS4 = (float4*)rS;
#pragma unroll
    for (int k = 0; k < 8; k++) {
        float2 e = v[BR[2*k]], o = v[BR[2*k] + 8];
        rS4[(t * RPITCH + 2*k) >> 1] = make_float4(e.x, e.y, o.x, o.y);
    }

    const float4* g4 = (const float4*)(Gh + ((size_t)k1 * N2 + 16 * t));
    float4 g[8];
#pragma unroll
    for (int m = 0; m < 8; m++) g[m] = g4[m];

    asm volatile("s_waitcnt lgkmcnt(0)" ::: "memory");
#pragma unroll
    for (int b = 0; b < 16; b++) v[b] = rS[b * RPITCH + t];

    fft16_fwd(v);

#pragma unroll
    for (int m = 0; m < 8; m++) {
        v[2*m]   = cmul(v[2*m],   make_float2(g[m].x, g[m].y));
        v[2*m+1] = cmul(v[2*m+1], make_float2(g[m].z, g[m].w));
    }

    fft16_inv(v);
#pragma unroll
    for (int b = 1; b < 16; b++) v[b] = cmulc(v[b], tab[b * RPITCH + t]);

#pragma unroll
    for (int m = 0; m < 8; m++)
        rS4[(t * RPITCH + 2*m) >> 1] = make_float4(v[2*m].x, v[2*m].y, v[2*m+1].x, v[2*m+1].y);
    asm volatile("s_waitcnt lgkmcnt(0)" ::: "memory");
#pragma unroll
    for (int c = 0; c < 16; c++) v[BR[c]] = rS[c * RPITCH + t];

    fft16_inv(v);

    {
        const float th = 2.f * PI_F / (float)N_FFT;
        float2 w = expif((float)(k1 * t) * th);
        const float2 stp = expif((float)(16 * k1) * th);
#pragma unroll
        for (int a = 0; a < 16; a++) {
            float2 r = cmul(v[a], w);
            bp[16 * a] = f2h(r);
            if (a < 15) w = cmul(w, stp);
        }
    }
}

// ---------------------------------------------------------------------------
// Inverse column FFT (512-pt DIT, brev load) over k1, scale, keep n1<256.
// ---------------------------------------------------------------------------
__global__ __launch_bounds__(512, 4) void inv_cols(
    const h2* __restrict__ src, float* __restrict__ out)
{
    __shared__ float4 s4[N1 * 16 / 2];            // 64 KB
    float2* s = (float2*)s4;
    const int tile = blockIdx.x, row = blockIdx.y, tid = threadIdx.x;
    const int n2base = tile * 16;
    const h2* srow = src + (size_t)row * N_FFT;
    const int cp = tid & 7, r8 = tid >> 3;        // r8 in [0,64)

#pragma unroll
    for (int i = 0; i < 8; i++) {
        int k1 = r8 + 64 * i;
        h4 v = *((const h4*)(srow + (size_t)k1 * N2 + n2base + 2 * cp));
        int p = brev9(k1);
        s4[p * 8 + cp] = make_float4((float)v.x, (float)v.y, (float)v.z, (float)v.w);
    }
    __syncthreads();

    const int c = tid & 15, r = tid >> 4;         // r in [0,32)

    const float2 w1c = make_float2(0.f, 1.f);     // conj(W_4^1) = i
    const float2 w2c = make_float2(R2_F, R2_F);   // conj(W_8^1)
    const float2 one = make_float2(1.f, 0.f);
#pragma unroll
    for (int o = 0; o < 2; o++) {
        int base = 8 * (r + 32 * o);
        float2 v[8];
#pragma unroll
        for (int m = 0; m < 8; m++) v[m] = s[(base + m) * 16 + c];
#pragma unroll
        for (int m = 0; m < 8; m += 2) {
            float2 a = v[m], b = v[m + 1];
            v[m] = cadd(a, b); v[m + 1] = csub(a, b);
        }
        dit4i(v[0], v[2], v[4], v[6], one, one);
        dit4i(v[1], v[3], v[5], v[7], w1c, w2c);
#pragma unroll
        for (int m = 0; m < 8; m++) s[(base + m) * 16 + c] = v[m];
    }
    __syncthreads();

    {
        float2 w2 = expif((float)(r & 7) * (PI_F / 16.f));
        float2 w1 = csq(w2);
#pragma unroll
        for (int qq = 0; qq < 4; qq++) {
            int g = (r >> 3) + 4 * qq;
            int p0 = g * 32 + (r & 7);
            float2 a0 = s[p0*16+c], a1 = s[(p0+8)*16+c], a2 = s[(p0+16)*16+c], a3 = s[(p0+24)*16+c];
            dit4i(a0, a1, a2, a3, w1, w2);
            s[p0*16+c] = a0; s[(p0+8)*16+c] = a1; s[(p0+16)*16+c] = a2; s[(p0+24)*16+c] = a3;
        }
    }
    __syncthreads();
    {
        float2 w2 = expif((float)r * (PI_F / 64.f));
        float2 w1 = csq(w2);
#pragma unroll
        for (int qq = 0; qq < 4; qq++) {
            int p0 = qq * 128 + r;
            float2 a0 = s[p0*16+c], a1 = s[(p0+32)*16+c], a2 = s[(p0+64)*16+c], a3 = s[(p0+96)*16+c];
            dit4i(a0, a1, a2, a3, w1, w2);
            s[p0*16+c] = a0; s[(p0+32)*16+c] = a1; s[(p0+64)*16+c] = a2; s[(p0+96)*16+c] = a3;
        }
    }
    __syncthreads();
    {
        float2 w2 = expif((float)r * (PI_F / 256.f));
        const float2 stp = make_float2(0.92387953251f, 0.38268343236f);
#pragma unroll
        for (int qq = 0; qq < 4; qq++) {
            int j = r + 32 * qq;
            float2 w1 = csq(w2);
            float2 a0 = s[j*16+c], a1 = s[(j+128)*16+c], a2 = s[(j+256)*16+c], a3 = s[(j+384)*16+c];
            dit4i(a0, a1, a2, a3, w1, w2);
            s[j*16+c] = a0; s[(j+128)*16+c] = a1; s[(j+256)*16+c] = a2; s[(j+384)*16+c] = a3;
            w2 = cmul(w2, stp);
        }
    }
    __syncthreads();

    const float scale = 1.0f / (float)N_FFT;
    float* out0 = out + (size_t)(2 * row) * T_LEN;
    float* out1 = out + (size_t)(2 * row + 1) * T_LEN;
#pragma unroll
    for (int i = 0; i < 4; i++) {
        int p = r8 + 64 * i;                      // p < 256
        float4 q = s4[p * 8 + cp];
        int n = p * N2 + n2base + 2 * cp;
        *(float2*)(out0 + n) = make_float2(q.x * scale, q.z * scale);
        *(float2*)(out1 + n) = make_float2(q.y * scale, q.w * scale);
    }
}

extern "C" void kernel_launch(void* const* d_in, const int* in_sizes, int n_in,
                              void* d_out, int out_size, void* d_ws, size_t ws_size,
                              hipStream_t stream) {
    const float* x    = (const float*)d_in[0];
    const float* filt = (const float*)d_in[1];
    float* out = (float*)d_out;

    h2* buf = (h2*)d_ws;                                                        // 67 MB
    float2* G = (float2*)((char*)d_ws + (size_t)CB * N_FFT * sizeof(h2));       // 1 MB

    fwd_cols<false><<<dim3(16, 1), 256, 0, stream>>>(filt, nullptr, 0LL, (void*)G);
    fwd_rows_g<<<N1 / 8, 128, 0, stream>>>(G);
    fwd_cols<true><<<dim3(16, CB), 256, 0, stream>>>(x, x + T_LEN, (long long)(2 * T_LEN), (void*)buf);
    mid_rows<<<(CB * N1) / 16, 256, 0, stream>>>(buf, G);
    inv_cols<<<dim3(16, CB), 512, 0, stream>>>(buf, out);
}